// Round 1
// baseline (487.968 us; speedup 1.0000x reference)
//
#include <hip/hip_runtime.h>

static constexpr int N = 50000;      // nodes
static constexpr int E = 1600000;    // edges
static constexpr int D = 128;        // feature dim (in == out)
static constexpr int NBLK = (N + 1023) / 1024;   // 49 scan blocks

// ---------------------------------------------------------------- CSR build
__global__ void count_k(const int* __restrict__ ei, int* __restrict__ cnt) {
    int e = blockIdx.x * blockDim.x + threadIdx.x;
    if (e < E) {
        int dst = ei[E + e];
        if ((unsigned)dst < (unsigned)N) atomicAdd(&cnt[dst], 1);
    }
}

__global__ void scan1_k(const int* __restrict__ cnt, int* __restrict__ off,
                        int* __restrict__ bsum) {
    __shared__ int s[1024];
    int tid = threadIdx.x;
    int i = blockIdx.x * 1024 + tid;
    int v = (i < N) ? cnt[i] : 0;
    s[tid] = v;
    __syncthreads();
    for (int d = 1; d < 1024; d <<= 1) {
        int add = (tid >= d) ? s[tid - d] : 0;
        int cur = s[tid];
        __syncthreads();
        s[tid] = cur + add;
        __syncthreads();
    }
    if (i < N) off[i] = s[tid] - v;              // exclusive within block
    if (tid == 1023) bsum[blockIdx.x] = s[1023]; // block total
}

__global__ void scan2_k(const int* __restrict__ bsum, int* __restrict__ boff) {
    __shared__ int s[64];
    int tid = threadIdx.x;
    int v = (tid < NBLK) ? bsum[tid] : 0;
    s[tid] = v;
    __syncthreads();
    for (int d = 1; d < 64; d <<= 1) {
        int add = (tid >= d) ? s[tid - d] : 0;
        int cur = s[tid];
        __syncthreads();
        s[tid] = cur + add;
        __syncthreads();
    }
    if (tid < NBLK) boff[tid] = s[tid] - v;      // exclusive across blocks
}

__global__ void scan3_k(int* __restrict__ off, const int* __restrict__ boff) {
    int i = blockIdx.x * blockDim.x + threadIdx.x;
    if (i < N) off[i] += boff[i >> 10];
}

// Buckets edges by dst. Uses off[] itself as the atomic cursor: after this
// kernel off[n] == end of node n's range (orig_off[n] + cnt[n]).
__global__ void scatter_k(const int* __restrict__ ei, const float* __restrict__ ea,
                          int* __restrict__ off, int* __restrict__ src_s,
                          float* __restrict__ u_s) {
    int e = blockIdx.x * blockDim.x + threadIdx.x;
    if (e < E) {
        int src = ei[e];
        int dst = ei[E + e];
        if ((unsigned)dst >= (unsigned)N) return;
        int p = atomicAdd(&off[dst], 1);
        src_s[p] = src;
        float u = ea[e];
        u_s[p] = fminf(fmaxf(u, 0.0f), 1.0f);
    }
}

// ------------------------------------------------- per-node edge aggregation
// One wave (64 lanes) per destination node; each lane owns 2 channels.
// a0[n] = (1/max(deg,1)) * sum (1-u)*x[src];  a1[n] = (1/max(deg,1)) * sum u*x[src]
__global__ __launch_bounds__(256) void edge_agg_k(
        const float* __restrict__ x, const int* __restrict__ off,
        const int* __restrict__ cnt, const int* __restrict__ src_s,
        const float* __restrict__ u_s, float* __restrict__ a0,
        float* __restrict__ a1) {
    int wave = (blockIdx.x * blockDim.x + threadIdx.x) >> 6;
    int lane = threadIdx.x & 63;
    if (wave >= N) return;
    int n   = wave;
    int end = off[n];          // post-scatter: == CSR end
    int deg = cnt[n];
    int beg = end - deg;

    float2 acc0 = {0.f, 0.f}, acc1 = {0.f, 0.f};
    const float* xl = x + lane * 2;

    for (int base = beg; base < end; base += 64) {
        int m = end - base; if (m > 64) m = 64;
        int   sl = 0; float ul = 0.f;
        if (lane < m) { sl = src_s[base + lane]; ul = u_s[base + lane]; }
        for (int j = 0; j < m; ++j) {
            int   src = __shfl(sl, j);
            float u   = __shfl(ul, j);
            float2 xv = *(const float2*)(xl + (size_t)src * D);
            float w0 = 1.0f - u;
            acc0.x += w0 * xv.x; acc0.y += w0 * xv.y;
            acc1.x += u  * xv.x; acc1.y += u  * xv.y;
        }
    }
    float inv = 1.0f / fmaxf((float)deg, 1.0f);
    float2 o0 = {acc0.x * inv, acc0.y * inv};
    float2 o1 = {acc1.x * inv, acc1.y * inv};
    *(float2*)(a0 + (size_t)n * D + lane * 2) = o0;
    *(float2*)(a1 + (size_t)n * D + lane * 2) = o1;
}

// ------------------------------------------------------------- output GEMM
// out = a0@W0 + a1@W1 + x@Wr + bias.  64x128 block tile, 256 threads,
// thread computes 8 rows x 4 cols. A staged transposed in LDS so the inner
// loop is 3x ds_read_b128 + 32 v_fma_f32 per k-step.
__global__ __launch_bounds__(256) void gemm_k(
        const float* __restrict__ a0, const float* __restrict__ a1,
        const float* __restrict__ x, const float* __restrict__ W,
        const float* __restrict__ Wr, const float* __restrict__ bias,
        float* __restrict__ out) {
    constexpr int ASTRIDE = 68;                 // floats; 272B, 16B-aligned rows
    __shared__ float AsT[32 * ASTRIDE];         // [k][row] transposed A tile
    __shared__ float Bs[32 * 128];              // [k][col]

    int t    = threadIdx.x;
    int tcol = t & 31;        // 4 cols each: 4*tcol..+3
    int trow = t >> 5;        // 8 rows each: 8*trow..+7
    int row0 = blockIdx.x * 64;

    float acc[8][4];
#pragma unroll
    for (int i = 0; i < 8; ++i)
#pragma unroll
        for (int j = 0; j < 4; ++j) acc[i][j] = 0.f;

    const float* Asrc[3] = {a0, a1, x};
    const float* Bsrc[3] = {W, W + D * D, Wr};

    for (int s = 0; s < 3; ++s) {
        const float* A = Asrc[s];
        const float* B = Bsrc[s];
        for (int kt = 0; kt < D; kt += 32) {
            // A tile 64x32 -> transposed LDS
#pragma unroll
            for (int l = 0; l < 2; ++l) {
                int idx = t * 2 + l;        // 0..511 float4 slots
                int r   = idx >> 3;         // 0..63
                int c4  = idx & 7;          // 0..7
                int grow = row0 + r;
                float4 v = make_float4(0.f, 0.f, 0.f, 0.f);
                if (grow < N) v = *(const float4*)(A + (size_t)grow * D + kt + c4 * 4);
                int c = c4 * 4;
                AsT[(c + 0) * ASTRIDE + r] = v.x;
                AsT[(c + 1) * ASTRIDE + r] = v.y;
                AsT[(c + 2) * ASTRIDE + r] = v.z;
                AsT[(c + 3) * ASTRIDE + r] = v.w;
            }
            // B tile 32x128
#pragma unroll
            for (int l = 0; l < 4; ++l) {
                int idx = t + l * 256;      // 0..1023 float4 slots
                int r   = idx >> 5;         // 0..31
                int c4  = idx & 31;         // 0..31
                float4 v = *(const float4*)(B + (size_t)(kt + r) * D + c4 * 4);
                *(float4*)&Bs[r * 128 + c4 * 4] = v;
            }
            __syncthreads();
#pragma unroll
            for (int kk = 0; kk < 32; ++kk) {
                float4 al = *(const float4*)&AsT[kk * ASTRIDE + trow * 8];
                float4 ah = *(const float4*)&AsT[kk * ASTRIDE + trow * 8 + 4];
                float4 b  = *(const float4*)&Bs[kk * 128 + tcol * 4];
                float a[8] = {al.x, al.y, al.z, al.w, ah.x, ah.y, ah.z, ah.w};
#pragma unroll
                for (int i = 0; i < 8; ++i) {
                    acc[i][0] += a[i] * b.x;
                    acc[i][1] += a[i] * b.y;
                    acc[i][2] += a[i] * b.z;
                    acc[i][3] += a[i] * b.w;
                }
            }
            __syncthreads();
        }
    }

    float4 bv = *(const float4*)(bias + tcol * 4);
#pragma unroll
    for (int i = 0; i < 8; ++i) {
        int grow = row0 + trow * 8 + i;
        if (grow < N) {
            float4 o = {acc[i][0] + bv.x, acc[i][1] + bv.y,
                        acc[i][2] + bv.z, acc[i][3] + bv.w};
            *(float4*)(out + (size_t)grow * D + tcol * 4) = o;
        }
    }
}

// ------------------------------------------------------------------ launch
extern "C" void kernel_launch(void* const* d_in, const int* in_sizes, int n_in,
                              void* d_out, int out_size, void* d_ws, size_t ws_size,
                              hipStream_t stream) {
    const float* x    = (const float*)d_in[0];
    const int*   ei   = (const int*)d_in[1];   // [2, E] int32 (src row, dst row)
    const float* ea   = (const float*)d_in[2]; // [E, 1]
    const float* W    = (const float*)d_in[3]; // [2, 128, 128]
    const float* Wr   = (const float*)d_in[4]; // [128, 128]
    const float* bias = (const float*)d_in[5]; // [128]
    float* out = (float*)d_out;

    char* ws = (char*)d_ws;
    size_t o = 0;
    auto alloc = [&](size_t bytes) -> void* {
        void* p = ws + o;
        o = (o + bytes + 255) & ~(size_t)255;
        return p;
    };
    int*   cnt   = (int*)alloc((size_t)N * 4);
    int*   off   = (int*)alloc((size_t)N * 4);
    int*   bsum  = (int*)alloc(64 * 4);
    int*   boff  = (int*)alloc(64 * 4);
    int*   src_s = (int*)alloc((size_t)E * 4);
    float* u_s   = (float*)alloc((size_t)E * 4);
    float* a0    = (float*)alloc((size_t)N * D * 4);
    float* a1    = (float*)alloc((size_t)N * D * 4);
    (void)ws_size; (void)in_sizes; (void)n_in; (void)out_size;

    hipMemsetAsync(cnt, 0, (size_t)N * 4, stream);
    count_k  <<<(E + 255) / 256, 256, 0, stream>>>(ei, cnt);
    scan1_k  <<<NBLK, 1024, 0, stream>>>(cnt, off, bsum);
    scan2_k  <<<1, 64, 0, stream>>>(bsum, boff);
    scan3_k  <<<(N + 255) / 256, 256, 0, stream>>>(off, boff);
    scatter_k<<<(E + 255) / 256, 256, 0, stream>>>(ei, ea, off, src_s, u_s);
    edge_agg_k<<<N / 4, 256, 0, stream>>>(x, off, cnt, src_s, u_s, a0, a1);
    gemm_k   <<<(N + 63) / 64, 256, 0, stream>>>(a0, a1, x, W, Wr, bias, out);
}

// Round 2
// 457.555 us; speedup vs baseline: 1.0665x; 1.0665x over previous
//
#include <hip/hip_runtime.h>

static constexpr int N = 50000;      // nodes
static constexpr int E = 1600000;    // edges
static constexpr int D = 128;        // feature dim (in == out)
static constexpr int NBLK = (N + 1023) / 1024;   // 49 scan blocks

// ---------------------------------------------------------------- CSR build
__global__ void count_k(const int* __restrict__ ei, int* __restrict__ cnt) {
    int e = blockIdx.x * blockDim.x + threadIdx.x;
    if (e < E) {
        int dst = ei[E + e];
        if ((unsigned)dst < (unsigned)N) atomicAdd(&cnt[dst], 1);
    }
}

__global__ void scan1_k(const int* __restrict__ cnt, int* __restrict__ off,
                        int* __restrict__ bsum) {
    __shared__ int s[1024];
    int tid = threadIdx.x;
    int i = blockIdx.x * 1024 + tid;
    int v = (i < N) ? cnt[i] : 0;
    s[tid] = v;
    __syncthreads();
    for (int d = 1; d < 1024; d <<= 1) {
        int add = (tid >= d) ? s[tid - d] : 0;
        int cur = s[tid];
        __syncthreads();
        s[tid] = cur + add;
        __syncthreads();
    }
    if (i < N) off[i] = s[tid] - v;              // exclusive within block
    if (tid == 1023) bsum[blockIdx.x] = s[1023]; // block total
}

__global__ void scan2_k(const int* __restrict__ bsum, int* __restrict__ boff) {
    __shared__ int s[64];
    int tid = threadIdx.x;
    int v = (tid < NBLK) ? bsum[tid] : 0;
    s[tid] = v;
    __syncthreads();
    for (int d = 1; d < 64; d <<= 1) {
        int add = (tid >= d) ? s[tid - d] : 0;
        int cur = s[tid];
        __syncthreads();
        s[tid] = cur + add;
        __syncthreads();
    }
    if (tid < NBLK) boff[tid] = s[tid] - v;      // exclusive across blocks
}

__global__ void scan3_k(int* __restrict__ off, const int* __restrict__ boff) {
    int i = blockIdx.x * blockDim.x + threadIdx.x;
    if (i < N) off[i] += boff[i >> 10];
}

// fp32 -> bf16 (RNE) conversion of x, vectorized: 4 elems/thread.
__global__ void cvt_k(const float* __restrict__ x, ushort* __restrict__ xb) {
    int i = blockIdx.x * blockDim.x + threadIdx.x;
    if (i < N * D / 4) {
        float4 v = ((const float4*)x)[i];
        uint a = __float_as_uint(v.x), b = __float_as_uint(v.y);
        uint c = __float_as_uint(v.z), d = __float_as_uint(v.w);
        a += 0x7fffu + ((a >> 16) & 1u);
        b += 0x7fffu + ((b >> 16) & 1u);
        c += 0x7fffu + ((c >> 16) & 1u);
        d += 0x7fffu + ((d >> 16) & 1u);
        ushort4 o = { (ushort)(a >> 16), (ushort)(b >> 16),
                      (ushort)(c >> 16), (ushort)(d >> 16) };
        ((ushort4*)xb)[i] = o;
    }
}

// Buckets edges by dst. Payload packed into ONE 8-byte word per edge:
// low 32 = src, high 32 = clipped u bits. Uses off[] as the atomic cursor:
// after this kernel off[n] == end of node n's range.
__global__ void scatter_k(const int* __restrict__ ei, const float* __restrict__ ea,
                          int* __restrict__ off,
                          unsigned long long* __restrict__ pay) {
    int e = blockIdx.x * blockDim.x + threadIdx.x;
    if (e < E) {
        int src = ei[e];
        int dst = ei[E + e];
        if ((unsigned)dst >= (unsigned)N) return;
        float u = fminf(fmaxf(ea[e], 0.0f), 1.0f);
        int p = atomicAdd(&off[dst], 1);
        pay[p] = ((unsigned long long)__float_as_uint(u) << 32) | (unsigned)src;
    }
}

// ------------------------------------------------- per-node edge aggregation
// One wave per destination node; each lane owns 2 channels (bf16 gather).
// a0[n] = (1/max(deg,1)) * sum (1-u)*x[src];  a1[n] = same with u.
__global__ __launch_bounds__(256) void edge_agg_k(
        const ushort* __restrict__ xb, const int* __restrict__ off,
        const int* __restrict__ cnt, const unsigned long long* __restrict__ pay,
        float* __restrict__ a0, float* __restrict__ a1) {
    int wave = (blockIdx.x * blockDim.x + threadIdx.x) >> 6;
    int lane = threadIdx.x & 63;
    if (wave >= N) return;
    int n   = wave;
    int end = off[n];          // post-scatter: == CSR end
    int deg = cnt[n];
    int beg = end - deg;

    float2 acc0 = {0.f, 0.f}, acc1 = {0.f, 0.f};
    const ushort* xl = xb + lane * 2;

    for (int base = beg; base < end; base += 64) {
        int m = end - base; if (m > 64) m = 64;
        int sl = 0; float ul = 0.f;
        if (lane < m) {
            unsigned long long v = pay[base + lane];
            sl = (int)(unsigned)(v & 0xffffffffull);
            ul = __uint_as_float((uint)(v >> 32));
        }
        for (int j = 0; j < m; ++j) {
            int   src = __shfl(sl, j);
            float u   = __shfl(ul, j);
            uint  p   = *(const uint*)(xl + (size_t)src * D);   // 2 bf16 ch
            float fx  = __uint_as_float((p & 0xffffu) << 16);
            float fy  = __uint_as_float(p & 0xffff0000u);
            float w0  = 1.0f - u;
            acc0.x += w0 * fx; acc0.y += w0 * fy;
            acc1.x += u  * fx; acc1.y += u  * fy;
        }
    }
    float inv = 1.0f / fmaxf((float)deg, 1.0f);
    float2 o0 = {acc0.x * inv, acc0.y * inv};
    float2 o1 = {acc1.x * inv, acc1.y * inv};
    *(float2*)(a0 + (size_t)n * D + lane * 2) = o0;
    *(float2*)(a1 + (size_t)n * D + lane * 2) = o1;
}

// ------------------------------------------------------------- output GEMM
// out = a0@W0 + a1@W1 + x@Wr + bias.  64x128 block tile, 256 threads,
// thread computes 8 rows x 4 cols. A staged transposed in LDS.
__global__ __launch_bounds__(256) void gemm_k(
        const float* __restrict__ a0, const float* __restrict__ a1,
        const float* __restrict__ x, const float* __restrict__ W,
        const float* __restrict__ Wr, const float* __restrict__ bias,
        float* __restrict__ out) {
    constexpr int ASTRIDE = 68;                 // floats; rows 16B-aligned
    __shared__ float AsT[32 * ASTRIDE];         // [k][row] transposed A tile
    __shared__ float Bs[32 * 128];              // [k][col]

    int t    = threadIdx.x;
    int tcol = t & 31;        // 4 cols each
    int trow = t >> 5;        // 8 rows each
    int row0 = blockIdx.x * 64;

    float acc[8][4];
#pragma unroll
    for (int i = 0; i < 8; ++i)
#pragma unroll
        for (int j = 0; j < 4; ++j) acc[i][j] = 0.f;

    const float* Asrc[3] = {a0, a1, x};
    const float* Bsrc[3] = {W, W + D * D, Wr};

    for (int s = 0; s < 3; ++s) {
        const float* A = Asrc[s];
        const float* B = Bsrc[s];
        for (int kt = 0; kt < D; kt += 32) {
#pragma unroll
            for (int l = 0; l < 2; ++l) {
                int idx = t * 2 + l;        // 0..511 float4 slots
                int r   = idx >> 3;         // 0..63
                int c4  = idx & 7;          // 0..7
                int grow = row0 + r;
                float4 v = make_float4(0.f, 0.f, 0.f, 0.f);
                if (grow < N) v = *(const float4*)(A + (size_t)grow * D + kt + c4 * 4);
                int c = c4 * 4;
                AsT[(c + 0) * ASTRIDE + r] = v.x;
                AsT[(c + 1) * ASTRIDE + r] = v.y;
                AsT[(c + 2) * ASTRIDE + r] = v.z;
                AsT[(c + 3) * ASTRIDE + r] = v.w;
            }
#pragma unroll
            for (int l = 0; l < 4; ++l) {
                int idx = t + l * 256;      // 0..1023 float4 slots
                int r   = idx >> 5;         // 0..31
                int c4  = idx & 31;         // 0..31
                float4 v = *(const float4*)(B + (size_t)(kt + r) * D + c4 * 4);
                *(float4*)&Bs[r * 128 + c4 * 4] = v;
            }
            __syncthreads();
#pragma unroll
            for (int kk = 0; kk < 32; ++kk) {
                float4 al = *(const float4*)&AsT[kk * ASTRIDE + trow * 8];
                float4 ah = *(const float4*)&AsT[kk * ASTRIDE + trow * 8 + 4];
                float4 b  = *(const float4*)&Bs[kk * 128 + tcol * 4];
                float a[8] = {al.x, al.y, al.z, al.w, ah.x, ah.y, ah.z, ah.w};
#pragma unroll
                for (int i = 0; i < 8; ++i) {
                    acc[i][0] += a[i] * b.x;
                    acc[i][1] += a[i] * b.y;
                    acc[i][2] += a[i] * b.z;
                    acc[i][3] += a[i] * b.w;
                }
            }
            __syncthreads();
        }
    }

    float4 bv = *(const float4*)(bias + tcol * 4);
#pragma unroll
    for (int i = 0; i < 8; ++i) {
        int grow = row0 + trow * 8 + i;
        if (grow < N) {
            float4 o = {acc[i][0] + bv.x, acc[i][1] + bv.y,
                        acc[i][2] + bv.z, acc[i][3] + bv.w};
            *(float4*)(out + (size_t)grow * D + tcol * 4) = o;
        }
    }
}

// ------------------------------------------------------------------ launch
extern "C" void kernel_launch(void* const* d_in, const int* in_sizes, int n_in,
                              void* d_out, int out_size, void* d_ws, size_t ws_size,
                              hipStream_t stream) {
    const float* x    = (const float*)d_in[0];
    const int*   ei   = (const int*)d_in[1];   // [2, E] int32
    const float* ea   = (const float*)d_in[2]; // [E, 1]
    const float* W    = (const float*)d_in[3]; // [2, 128, 128]
    const float* Wr   = (const float*)d_in[4]; // [128, 128]
    const float* bias = (const float*)d_in[5]; // [128]
    float* out = (float*)d_out;

    char* ws = (char*)d_ws;
    size_t o = 0;
    auto alloc = [&](size_t bytes) -> void* {
        void* p = ws + o;
        o = (o + bytes + 255) & ~(size_t)255;
        return p;
    };
    int*    cnt  = (int*)alloc((size_t)N * 4);
    int*    off  = (int*)alloc((size_t)N * 4);
    int*    bsum = (int*)alloc(64 * 4);
    int*    boff = (int*)alloc(64 * 4);
    unsigned long long* pay = (unsigned long long*)alloc((size_t)E * 8);
    ushort* xb   = (ushort*)alloc((size_t)N * D * 2);
    float*  a0   = (float*)alloc((size_t)N * D * 4);
    float*  a1   = (float*)alloc((size_t)N * D * 4);
    (void)ws_size; (void)in_sizes; (void)n_in; (void)out_size;

    hipMemsetAsync(cnt, 0, (size_t)N * 4, stream);
    cvt_k    <<<(N * D / 4 + 255) / 256, 256, 0, stream>>>(x, xb);
    count_k  <<<(E + 255) / 256, 256, 0, stream>>>(ei, cnt);
    scan1_k  <<<NBLK, 1024, 0, stream>>>(cnt, off, bsum);
    scan2_k  <<<1, 64, 0, stream>>>(bsum, boff);
    scan3_k  <<<(N + 255) / 256, 256, 0, stream>>>(off, boff);
    scatter_k<<<(E + 255) / 256, 256, 0, stream>>>(ei, ea, off, pay);
    edge_agg_k<<<N / 4, 256, 0, stream>>>(xb, off, cnt, pay, a0, a1);
    gemm_k   <<<(N + 63) / 64, 256, 0, stream>>>(a0, a1, x, W, Wr, bias, out);
}

// Round 3
// 364.094 us; speedup vs baseline: 1.3402x; 1.2567x over previous
//
#include <hip/hip_runtime.h>

static constexpr int N = 50000;      // nodes
static constexpr int E = 1600000;    // edges
static constexpr int D = 128;        // feature dim (in == out)
static constexpr int NBLK = (N + 1023) / 1024;   // 49 scan blocks

typedef __attribute__((ext_vector_type(8))) short short8;   // 8 bf16
typedef __attribute__((ext_vector_type(4))) float f32x4;    // 4 fp32

__device__ __forceinline__ uint bf16rne2(float a, float b) {
    uint ua = __float_as_uint(a), ub = __float_as_uint(b);
    ua += 0x7fffu + ((ua >> 16) & 1u);
    ub += 0x7fffu + ((ub >> 16) & 1u);
    return (ua >> 16) | (ub & 0xffff0000u);
}

// ---------------------------------------------------------------- CSR build
__global__ void count_k(const int* __restrict__ ei, int* __restrict__ cnt) {
    int e = blockIdx.x * blockDim.x + threadIdx.x;
    if (e < E) {
        int dst = ei[E + e];
        if ((unsigned)dst < (unsigned)N) atomicAdd(&cnt[dst], 1);
    }
}

__global__ void scan1_k(const int* __restrict__ cnt, int* __restrict__ off,
                        int* __restrict__ bsum) {
    __shared__ int s[1024];
    int tid = threadIdx.x;
    int i = blockIdx.x * 1024 + tid;
    int v = (i < N) ? cnt[i] : 0;
    s[tid] = v;
    __syncthreads();
    for (int d = 1; d < 1024; d <<= 1) {
        int add = (tid >= d) ? s[tid - d] : 0;
        int cur = s[tid];
        __syncthreads();
        s[tid] = cur + add;
        __syncthreads();
    }
    if (i < N) off[i] = s[tid] - v;              // exclusive within block
    if (tid == 1023) bsum[blockIdx.x] = s[1023]; // block total
}

__global__ void scan2_k(const int* __restrict__ bsum, int* __restrict__ boff) {
    __shared__ int s[64];
    int tid = threadIdx.x;
    int v = (tid < NBLK) ? bsum[tid] : 0;
    s[tid] = v;
    __syncthreads();
    for (int d = 1; d < 64; d <<= 1) {
        int add = (tid >= d) ? s[tid - d] : 0;
        int cur = s[tid];
        __syncthreads();
        s[tid] = cur + add;
        __syncthreads();
    }
    if (tid < NBLK) boff[tid] = s[tid] - v;      // exclusive across blocks
}

__global__ void scan3_k(int* __restrict__ off, const int* __restrict__ boff) {
    int i = blockIdx.x * blockDim.x + threadIdx.x;
    if (i < N) off[i] += boff[i >> 10];
}

// fp32 -> bf16 (RNE) conversion of x, vectorized: 4 elems/thread.
__global__ void cvt_k(const float* __restrict__ x, ushort* __restrict__ xb) {
    int i = blockIdx.x * blockDim.x + threadIdx.x;
    if (i < N * D / 4) {
        float4 v = ((const float4*)x)[i];
        uint2 o = { bf16rne2(v.x, v.y), bf16rne2(v.z, v.w) };
        ((uint2*)xb)[i] = o;
    }
}

// Weight transpose + bf16: Wt[n][r], r in [0,384): r<256 -> W (both slots,
// contiguous since W[k][d][e] flat => row r is W[r*128+n]); r>=256 -> Wr.
__global__ void cvt_w_k(const float* __restrict__ W, const float* __restrict__ Wr,
                        ushort* __restrict__ Wt) {
    int i = blockIdx.x * blockDim.x + threadIdx.x;
    if (i < 128 * 384) {
        int n = i / 384, r = i % 384;
        float v = (r < 256) ? W[(size_t)r * 128 + n] : Wr[(size_t)(r - 256) * 128 + n];
        uint u = __float_as_uint(v);
        u += 0x7fffu + ((u >> 16) & 1u);
        Wt[(size_t)n * 384 + r] = (ushort)(u >> 16);
    }
}

// Buckets edges by dst. Payload is ONE 4-byte word per edge:
// low 16 = src (N<65536), high 16 = u quantized to fixed-point /65535.
// Uses off[] as the atomic cursor: after this kernel off[n] == range end.
__global__ void scatter_k(const int* __restrict__ ei, const float* __restrict__ ea,
                          int* __restrict__ off, uint* __restrict__ pay) {
    int e = blockIdx.x * blockDim.x + threadIdx.x;
    if (e < E) {
        int src = ei[e];
        int dst = ei[E + e];
        if ((unsigned)dst >= (unsigned)N) return;
        float u = fminf(fmaxf(ea[e], 0.0f), 1.0f);
        uint u16 = (uint)(u * 65535.0f + 0.5f);
        int p = atomicAdd(&off[dst], 1);
        pay[p] = (u16 << 16) | (uint)src;
    }
}

// ------------------------------------------------- per-node edge aggregation
// One wave per destination node. 16 lanes serve one edge (lane&15 -> channel
// block of 8), 4 edges in flight per wave-instruction via dwordx4 gather.
// Outputs written as bf16 rows (GEMM A operand).
__global__ __launch_bounds__(256) void edge_agg_k(
        const ushort* __restrict__ xb, const int* __restrict__ off,
        const int* __restrict__ cnt, const uint* __restrict__ pay,
        ushort* __restrict__ a0b, ushort* __restrict__ a1b) {
    int wave = (blockIdx.x * blockDim.x + threadIdx.x) >> 6;
    int lane = threadIdx.x & 63;
    if (wave >= N) return;
    int n   = wave;
    int end = off[n];          // post-scatter: == CSR end
    int deg = cnt[n];
    int beg = end - deg;

    int grp = lane >> 4;       // which of 4 concurrent edges
    int cl  = lane & 15;       // channel block: chs [8*cl, 8*cl+8)

    float accA[8], accB[8];
#pragma unroll
    for (int k = 0; k < 8; ++k) { accA[k] = 0.f; accB[k] = 0.f; }

    for (int base = beg; base < end; base += 64) {
        int m = end - base; if (m > 64) m = 64;
        uint pv = (lane < m) ? pay[base + lane] : 0u;
        int jmax = (m + 3) >> 2;
        for (int j = 0; j < jmax; ++j) {
            int s = 4 * j + grp;
            uint pl = (uint)__shfl((int)pv, s);
            if (s < m) {
                int   src = (int)(pl & 0xffffu);
                float u   = (float)(pl >> 16) * (1.0f / 65535.0f);
                float w0  = 1.0f - u;
                uint4 v = *(const uint4*)(xb + (size_t)src * D + cl * 8);
                uint w[4] = {v.x, v.y, v.z, v.w};
#pragma unroll
                for (int q = 0; q < 4; ++q) {
                    float lo = __uint_as_float(w[q] << 16);
                    float hi = __uint_as_float(w[q] & 0xffff0000u);
                    accA[2 * q]     += w0 * lo;
                    accA[2 * q + 1] += w0 * hi;
                    accB[2 * q]     += u * lo;
                    accB[2 * q + 1] += u * hi;
                }
            }
        }
    }
    // reduce the 4 edge-groups (lanes differing in bits 4,5 share channels)
#pragma unroll
    for (int k = 0; k < 8; ++k) {
        accA[k] += __shfl_xor(accA[k], 16);
        accA[k] += __shfl_xor(accA[k], 32);
        accB[k] += __shfl_xor(accB[k], 16);
        accB[k] += __shfl_xor(accB[k], 32);
    }
    float inv = 1.0f / fmaxf((float)deg, 1.0f);
    if (lane < 16) {
        uint4 oa = { bf16rne2(accA[0] * inv, accA[1] * inv),
                     bf16rne2(accA[2] * inv, accA[3] * inv),
                     bf16rne2(accA[4] * inv, accA[5] * inv),
                     bf16rne2(accA[6] * inv, accA[7] * inv) };
        uint4 ob = { bf16rne2(accB[0] * inv, accB[1] * inv),
                     bf16rne2(accB[2] * inv, accB[3] * inv),
                     bf16rne2(accB[4] * inv, accB[5] * inv),
                     bf16rne2(accB[6] * inv, accB[7] * inv) };
        *(uint4*)(a0b + (size_t)n * D + cl * 8) = oa;
        *(uint4*)(a1b + (size_t)n * D + cl * 8) = ob;
    }
}

// ------------------------------------------------------------- output GEMM
// out = [a0|a1|x] (M=50000, K=384, bf16) @ Wt^T (Wt is [n][k]) + bias.
// 128x128 block tile, 4 waves in 2x2, 16x16x32 bf16 MFMA, BK=32, 12 K-iters.
__global__ __launch_bounds__(256) void gemm_k(
        const ushort* __restrict__ a0b, const ushort* __restrict__ a1b,
        const ushort* __restrict__ xb, const ushort* __restrict__ Wt,
        const float* __restrict__ bias, float* __restrict__ out) {
    constexpr int LST = 40;                     // LDS row stride (elems), pad 8
    __shared__ ushort As[128 * LST];
    __shared__ ushort Bs[128 * LST];

    int t    = threadIdx.x;
    int lane = t & 63;
    int w    = t >> 6;
    int r2   = w >> 1, c2 = w & 1;
    int q    = lane >> 4;
    int l16  = lane & 15;
    int row0 = blockIdx.x * 128;

    f32x4 acc[4][4];
#pragma unroll
    for (int i = 0; i < 4; ++i)
#pragma unroll
        for (int j = 0; j < 4; ++j) acc[i][j] = 0.f;

    const ushort* Asrc[3] = {a0b, a1b, xb};

    for (int kt = 0; kt < 384; kt += 32) {
        const ushort* Ab = Asrc[kt >> 7];
        int ko = kt & 127;
#pragma unroll
        for (int h = 0; h < 2; ++h) {
            int s  = t + h * 256;      // 0..511 uint4 slots
            int r  = s >> 2;           // 0..127
            int q4 = s & 3;            // 0..3 (8-elem groups)
            int rg = row0 + r;
            uint4 av = make_uint4(0, 0, 0, 0);
            if (rg < N) av = *(const uint4*)(Ab + (size_t)rg * 128 + ko + q4 * 8);
            *(uint4*)&As[r * LST + q4 * 8] = av;
            uint4 bv = *(const uint4*)(Wt + (size_t)r * 384 + kt + q4 * 8);
            *(uint4*)&Bs[r * LST + q4 * 8] = bv;
        }
        __syncthreads();
        short8 af[4], bf[4];
#pragma unroll
        for (int mt = 0; mt < 4; ++mt)
            af[mt] = *(const short8*)&As[(r2 * 64 + mt * 16 + l16) * LST + q * 8];
#pragma unroll
        for (int nt = 0; nt < 4; ++nt)
            bf[nt] = *(const short8*)&Bs[(c2 * 64 + nt * 16 + l16) * LST + q * 8];
#pragma unroll
        for (int mt = 0; mt < 4; ++mt)
#pragma unroll
            for (int nt = 0; nt < 4; ++nt)
                acc[mt][nt] = __builtin_amdgcn_mfma_f32_16x16x32_bf16(
                    af[mt], bf[nt], acc[mt][nt], 0, 0, 0);
        __syncthreads();
    }

#pragma unroll
    for (int nt = 0; nt < 4; ++nt) {
        int col = c2 * 64 + nt * 16 + l16;
        float bb = bias[col];
#pragma unroll
        for (int mt = 0; mt < 4; ++mt) {
#pragma unroll
            for (int r = 0; r < 4; ++r) {
                int row = row0 + r2 * 64 + mt * 16 + q * 4 + r;
                if (row < N) out[(size_t)row * 128 + col] = acc[mt][nt][r] + bb;
            }
        }
    }
}

// ------------------------------------------------------------------ launch
extern "C" void kernel_launch(void* const* d_in, const int* in_sizes, int n_in,
                              void* d_out, int out_size, void* d_ws, size_t ws_size,
                              hipStream_t stream) {
    const float* x    = (const float*)d_in[0];
    const int*   ei   = (const int*)d_in[1];   // [2, E] int32
    const float* ea   = (const float*)d_in[2]; // [E, 1]
    const float* W    = (const float*)d_in[3]; // [2, 128, 128]
    const float* Wr   = (const float*)d_in[4]; // [128, 128]
    const float* bias = (const float*)d_in[5]; // [128]
    float* out = (float*)d_out;

    char* ws = (char*)d_ws;
    size_t o = 0;
    auto alloc = [&](size_t bytes) -> void* {
        void* p = ws + o;
        o = (o + bytes + 255) & ~(size_t)255;
        return p;
    };
    int*    cnt  = (int*)alloc((size_t)N * 4);
    int*    off  = (int*)alloc((size_t)N * 4);
    int*    bsum = (int*)alloc(64 * 4);
    int*    boff = (int*)alloc(64 * 4);
    uint*   pay  = (uint*)alloc((size_t)E * 4);
    ushort* xb   = (ushort*)alloc((size_t)N * D * 2);
    ushort* a0b  = (ushort*)alloc((size_t)N * D * 2);
    ushort* a1b  = (ushort*)alloc((size_t)N * D * 2);
    ushort* Wt   = (ushort*)alloc((size_t)128 * 384 * 2);
    (void)ws_size; (void)in_sizes; (void)n_in; (void)out_size;

    hipMemsetAsync(cnt, 0, (size_t)N * 4, stream);
    cvt_k    <<<(N * D / 4 + 255) / 256, 256, 0, stream>>>(x, xb);
    cvt_w_k  <<<(128 * 384 + 255) / 256, 256, 0, stream>>>(W, Wr, Wt);
    count_k  <<<(E + 255) / 256, 256, 0, stream>>>(ei, cnt);
    scan1_k  <<<NBLK, 1024, 0, stream>>>(cnt, off, bsum);
    scan2_k  <<<1, 64, 0, stream>>>(bsum, boff);
    scan3_k  <<<(N + 255) / 256, 256, 0, stream>>>(off, boff);
    scatter_k<<<(E + 255) / 256, 256, 0, stream>>>(ei, ea, off, pay);
    edge_agg_k<<<N / 4, 256, 0, stream>>>(xb, off, cnt, pay, a0b, a1b);
    gemm_k   <<<(N + 127) / 128, 256, 0, stream>>>(a0b, a1b, xb, Wt, bias, out);
}

// Round 4
// 236.982 us; speedup vs baseline: 2.0591x; 1.5364x over previous
//
#include <hip/hip_runtime.h>

static constexpr int N = 50000;      // nodes
static constexpr int E = 1600000;    // edges
static constexpr int D = 128;        // feature dim (in == out)
static constexpr int NB = (N + 63) / 64;         // 782 buckets of 64 nodes
static constexpr int BINBLK = 200;               // bin blocks
static constexpr int CHUNK = E / BINBLK;         // 8000 edges per bin block
static constexpr int BKT_CAP = 3072;             // mean 2048, sigma ~45

typedef __attribute__((ext_vector_type(8))) short short8;   // 8 bf16
typedef __attribute__((ext_vector_type(4))) float f32x4;    // 4 fp32

__device__ __forceinline__ uint bf16rne2(float a, float b) {
    uint ua = __float_as_uint(a), ub = __float_as_uint(b);
    ua += 0x7fffu + ((ua >> 16) & 1u);
    ub += 0x7fffu + ((ub >> 16) & 1u);
    return (ua >> 16) | (ub & 0xffff0000u);
}

// fp32 -> bf16 (RNE) conversion of x, vectorized: 4 elems/thread.
__global__ void cvt_k(const float* __restrict__ x, ushort* __restrict__ xb) {
    int i = blockIdx.x * blockDim.x + threadIdx.x;
    if (i < N * D / 4) {
        float4 v = ((const float4*)x)[i];
        uint2 o = { bf16rne2(v.x, v.y), bf16rne2(v.z, v.w) };
        ((uint2*)xb)[i] = o;
    }
}

// Weight transpose + bf16: Wt[n][r], r in [0,384): r<256 -> W, r>=256 -> Wr.
__global__ void cvt_w_k(const float* __restrict__ W, const float* __restrict__ Wr,
                        ushort* __restrict__ Wt) {
    int i = blockIdx.x * blockDim.x + threadIdx.x;
    if (i < 128 * 384) {
        int n = i / 384, r = i % 384;
        float v = (r < 256) ? W[(size_t)r * 128 + n] : Wr[(size_t)(r - 256) * 128 + n];
        uint u = __float_as_uint(v);
        u += 0x7fffu + ((u >> 16) & 1u);
        Wt[(size_t)n * 384 + r] = (ushort)(u >> 16);
    }
}

// ------------------------------------------------------- two-level binning
// Coarse bucket histogram (bucket = dst >> 6), LDS pre-aggregated.
__global__ __launch_bounds__(256) void bucket_count_k(const int* __restrict__ ei,
                                                      int* __restrict__ cnt_b) {
    __shared__ int hist[NB];
    int t = threadIdx.x;
    for (int j = t; j < NB; j += 256) hist[j] = 0;
    __syncthreads();
    int b0 = blockIdx.x * CHUNK;
    for (int i = b0 + t; i < b0 + CHUNK; i += 256) {
        int dst = ei[E + i];
        if ((unsigned)dst < (unsigned)N) atomicAdd(&hist[dst >> 6], 1);
    }
    __syncthreads();
    for (int j = t; j < NB; j += 256) {
        int c = hist[j];
        if (c) atomicAdd(&cnt_b[j], c);
    }
}

// Exclusive scan of 782 bucket counts -> bkt_off (preserved) + cursor (mutable).
__global__ __launch_bounds__(1024) void bucket_scan_k(const int* __restrict__ cnt_b,
                                                      int* __restrict__ bkt_off,
                                                      int* __restrict__ cursor) {
    __shared__ int s[1024];
    int tid = threadIdx.x;
    int v = (tid < NB) ? cnt_b[tid] : 0;
    s[tid] = v;
    __syncthreads();
    for (int d = 1; d < 1024; d <<= 1) {
        int add = (tid >= d) ? s[tid - d] : 0;
        int cur = s[tid];
        __syncthreads();
        s[tid] = cur + add;
        __syncthreads();
    }
    if (tid < NB) {
        int e = s[tid] - v;
        bkt_off[tid] = e;
        cursor[tid] = e;
    }
}

// Partition edges into coarse buckets. Per-block LDS ranking + one global
// atomic per (block,bucket) => global writes are contiguous ~10-edge runs.
// Payload: bits[15:0]=src, [21:16]=dst&63, [31:22]=u quantized /1023.
__global__ __launch_bounds__(256) void bin_k(const int* __restrict__ ei,
                                             const float* __restrict__ ea,
                                             int* __restrict__ cursor,
                                             uint* __restrict__ pay) {
    __shared__ int hist[NB];
    __shared__ int base[NB];
    int t = threadIdx.x;
    int b0 = blockIdx.x * CHUNK;
    for (int j = t; j < NB; j += 256) hist[j] = 0;
    __syncthreads();
    for (int i = b0 + t; i < b0 + CHUNK; i += 256) {
        int dst = ei[E + i];
        if ((unsigned)dst < (unsigned)N) atomicAdd(&hist[dst >> 6], 1);
    }
    __syncthreads();
    for (int j = t; j < NB; j += 256) {
        int c = hist[j];
        base[j] = c ? atomicAdd(&cursor[j], c) : 0;
        hist[j] = 0;
    }
    __syncthreads();
    for (int i = b0 + t; i < b0 + CHUNK; i += 256) {
        int dst = ei[E + i];
        if ((unsigned)dst >= (unsigned)N) continue;
        int src = ei[i];
        float u = fminf(fmaxf(ea[i], 0.0f), 1.0f);
        uint u10 = (uint)(u * 1023.0f + 0.5f);
        int bkt = dst >> 6;
        int r = atomicAdd(&hist[bkt], 1);
        pay[base[bkt] + r] = (u10 << 22) | ((uint)(dst & 63) << 16) | (uint)src;
    }
}

// Per-bucket LDS sort by dst_low -> coalesced sorted CSR + off/cnt.
// off[n] = END of node n's range (edge_agg's R3 convention), cnt[n] = degree.
__global__ __launch_bounds__(256) void bucket_sort_k(
        const int* __restrict__ bkt_off, const int* __restrict__ cursor,
        const uint* __restrict__ pay_in, uint* __restrict__ pay_out,
        int* __restrict__ off, int* __restrict__ cnt) {
    __shared__ uint srt[BKT_CAP];
    __shared__ int hist[64];
    __shared__ int off64[65];
    int b = blockIdx.x, t = threadIdx.x;
    int beg = bkt_off[b];
    int end = cursor[b];              // post-bin: beg + bucket count
    int c = end - beg;
    if (c > BKT_CAP) c = BKT_CAP;     // statistically impossible; safety
    if (t < 64) hist[t] = 0;
    __syncthreads();
    uint mypay[12]; int myrank[12];
#pragma unroll
    for (int k = 0; k < 12; ++k) {
        int i = t + k * 256;
        if (i < c) {
            uint p = pay_in[beg + i];
            mypay[k] = p;
            myrank[k] = atomicAdd(&hist[(p >> 16) & 63], 1);
        }
    }
    __syncthreads();
    if (t < 64) {
        int v = hist[t];
        int s = v;
        for (int d = 1; d < 64; d <<= 1) {
            int o = __shfl_up(s, d);
            if (t >= d) s += o;
        }
        off64[t] = s - v;             // exclusive
        if (t == 63) off64[64] = s;
    }
    __syncthreads();
#pragma unroll
    for (int k = 0; k < 12; ++k) {
        int i = t + k * 256;
        if (i < c) {
            uint p = mypay[k];
            srt[off64[(p >> 16) & 63] + myrank[k]] = p;
        }
    }
    __syncthreads();
    for (int i = t; i < c; i += 256) pay_out[beg + i] = srt[i];   // coalesced
    if (t < 64) {
        int node = b * 64 + t;
        if (node < N) {
            off[node] = beg + off64[t + 1];          // range end
            cnt[node] = off64[t + 1] - off64[t];
        }
    }
}

// ------------------------------------------------- per-node edge aggregation
// One wave per destination node; 16 lanes per edge (lane&15 -> 8-ch block),
// 4 edge-groups x 2-deep pipeline = 8 row-gathers in flight per wave.
__global__ __launch_bounds__(256) void edge_agg_k(
        const ushort* __restrict__ xb, const int* __restrict__ off,
        const int* __restrict__ cnt, const uint* __restrict__ pay,
        ushort* __restrict__ a0b, ushort* __restrict__ a1b) {
    int wave = (blockIdx.x * blockDim.x + threadIdx.x) >> 6;
    int lane = threadIdx.x & 63;
    if (wave >= N) return;
    int n   = wave;
    int end = off[n];
    int deg = cnt[n];
    int beg = end - deg;

    int grp = lane >> 4;
    int cl  = lane & 15;

    float accA[8], accB[8];
#pragma unroll
    for (int k = 0; k < 8; ++k) { accA[k] = 0.f; accB[k] = 0.f; }

    for (int base = beg; base < end; base += 64) {
        int m = end - base; if (m > 64) m = 64;
        uint pv = (lane < m) ? pay[base + lane] : 0u;
        for (int j = 0; 4 * j < m; j += 2) {
            int s0 = 4 * j + grp;
            int s1 = s0 + 4;
            uint p0 = (uint)__shfl((int)pv, s0);
            uint p1 = (uint)__shfl((int)pv, s1);
            bool g0 = s0 < m, g1 = s1 < m;
            uint4 v0 = make_uint4(0, 0, 0, 0), v1 = make_uint4(0, 0, 0, 0);
            if (g0) v0 = *(const uint4*)(xb + (size_t)(p0 & 0xffffu) * D + cl * 8);
            if (g1) v1 = *(const uint4*)(xb + (size_t)(p1 & 0xffffu) * D + cl * 8);
            if (g0) {
                float u  = (float)(p0 >> 22) * (1.0f / 1023.0f);
                float w0 = 1.0f - u;
                uint w[4] = {v0.x, v0.y, v0.z, v0.w};
#pragma unroll
                for (int q = 0; q < 4; ++q) {
                    float lo = __uint_as_float(w[q] << 16);
                    float hi = __uint_as_float(w[q] & 0xffff0000u);
                    accA[2 * q]     += w0 * lo;
                    accA[2 * q + 1] += w0 * hi;
                    accB[2 * q]     += u * lo;
                    accB[2 * q + 1] += u * hi;
                }
            }
            if (g1) {
                float u  = (float)(p1 >> 22) * (1.0f / 1023.0f);
                float w0 = 1.0f - u;
                uint w[4] = {v1.x, v1.y, v1.z, v1.w};
#pragma unroll
                for (int q = 0; q < 4; ++q) {
                    float lo = __uint_as_float(w[q] << 16);
                    float hi = __uint_as_float(w[q] & 0xffff0000u);
                    accA[2 * q]     += w0 * lo;
                    accA[2 * q + 1] += w0 * hi;
                    accB[2 * q]     += u * lo;
                    accB[2 * q + 1] += u * hi;
                }
            }
        }
    }
#pragma unroll
    for (int k = 0; k < 8; ++k) {
        accA[k] += __shfl_xor(accA[k], 16);
        accA[k] += __shfl_xor(accA[k], 32);
        accB[k] += __shfl_xor(accB[k], 16);
        accB[k] += __shfl_xor(accB[k], 32);
    }
    float inv = 1.0f / fmaxf((float)deg, 1.0f);
    if (lane < 16) {
        uint4 oa = { bf16rne2(accA[0] * inv, accA[1] * inv),
                     bf16rne2(accA[2] * inv, accA[3] * inv),
                     bf16rne2(accA[4] * inv, accA[5] * inv),
                     bf16rne2(accA[6] * inv, accA[7] * inv) };
        uint4 ob = { bf16rne2(accB[0] * inv, accB[1] * inv),
                     bf16rne2(accB[2] * inv, accB[3] * inv),
                     bf16rne2(accB[4] * inv, accB[5] * inv),
                     bf16rne2(accB[6] * inv, accB[7] * inv) };
        *(uint4*)(a0b + (size_t)n * D + cl * 8) = oa;
        *(uint4*)(a1b + (size_t)n * D + cl * 8) = ob;
    }
}

// ------------------------------------------------------------- output GEMM
// out = [a0|a1|x] (M=50000, K=384, bf16) @ Wt^T + bias. 128x128 tile,
// 4 waves 2x2, 16x16x32 bf16 MFMA, BK=32.
__global__ __launch_bounds__(256) void gemm_k(
        const ushort* __restrict__ a0b, const ushort* __restrict__ a1b,
        const ushort* __restrict__ xb, const ushort* __restrict__ Wt,
        const float* __restrict__ bias, float* __restrict__ out) {
    constexpr int LST = 40;
    __shared__ ushort As[128 * LST];
    __shared__ ushort Bs[128 * LST];

    int t    = threadIdx.x;
    int lane = t & 63;
    int w    = t >> 6;
    int r2   = w >> 1, c2 = w & 1;
    int q    = lane >> 4;
    int l16  = lane & 15;
    int row0 = blockIdx.x * 128;

    f32x4 acc[4][4];
#pragma unroll
    for (int i = 0; i < 4; ++i)
#pragma unroll
        for (int j = 0; j < 4; ++j) acc[i][j] = 0.f;

    const ushort* Asrc[3] = {a0b, a1b, xb};

    for (int kt = 0; kt < 384; kt += 32) {
        const ushort* Ab = Asrc[kt >> 7];
        int ko = kt & 127;
#pragma unroll
        for (int h = 0; h < 2; ++h) {
            int s  = t + h * 256;
            int r  = s >> 2;
            int q4 = s & 3;
            int rg = row0 + r;
            uint4 av = make_uint4(0, 0, 0, 0);
            if (rg < N) av = *(const uint4*)(Ab + (size_t)rg * 128 + ko + q4 * 8);
            *(uint4*)&As[r * LST + q4 * 8] = av;
            uint4 bv = *(const uint4*)(Wt + (size_t)r * 384 + kt + q4 * 8);
            *(uint4*)&Bs[r * LST + q4 * 8] = bv;
        }
        __syncthreads();
        short8 af[4], bf[4];
#pragma unroll
        for (int mt = 0; mt < 4; ++mt)
            af[mt] = *(const short8*)&As[(r2 * 64 + mt * 16 + l16) * LST + q * 8];
#pragma unroll
        for (int nt = 0; nt < 4; ++nt)
            bf[nt] = *(const short8*)&Bs[(c2 * 64 + nt * 16 + l16) * LST + q * 8];
#pragma unroll
        for (int mt = 0; mt < 4; ++mt)
#pragma unroll
            for (int nt = 0; nt < 4; ++nt)
                acc[mt][nt] = __builtin_amdgcn_mfma_f32_16x16x32_bf16(
                    af[mt], bf[nt], acc[mt][nt], 0, 0, 0);
        __syncthreads();
    }

#pragma unroll
    for (int nt = 0; nt < 4; ++nt) {
        int col = c2 * 64 + nt * 16 + l16;
        float bb = bias[col];
#pragma unroll
        for (int mt = 0; mt < 4; ++mt) {
#pragma unroll
            for (int r = 0; r < 4; ++r) {
                int row = row0 + r2 * 64 + mt * 16 + q * 4 + r;
                if (row < N) out[(size_t)row * 128 + col] = acc[mt][nt][r] + bb;
            }
        }
    }
}

// ------------------------------------------------------------------ launch
extern "C" void kernel_launch(void* const* d_in, const int* in_sizes, int n_in,
                              void* d_out, int out_size, void* d_ws, size_t ws_size,
                              hipStream_t stream) {
    const float* x    = (const float*)d_in[0];
    const int*   ei   = (const int*)d_in[1];   // [2, E] int32
    const float* ea   = (const float*)d_in[2]; // [E, 1]
    const float* W    = (const float*)d_in[3]; // [2, 128, 128]
    const float* Wr   = (const float*)d_in[4]; // [128, 128]
    const float* bias = (const float*)d_in[5]; // [128]
    float* out = (float*)d_out;

    char* ws = (char*)d_ws;
    size_t o = 0;
    auto alloc = [&](size_t bytes) -> void* {
        void* p = ws + o;
        o = (o + bytes + 255) & ~(size_t)255;
        return p;
    };
    int*    cnt_b   = (int*)alloc((size_t)NB * 4);
    int*    bkt_off = (int*)alloc((size_t)NB * 4);
    int*    cursor  = (int*)alloc((size_t)NB * 4);
    uint*   pay     = (uint*)alloc((size_t)E * 4);
    uint*   pay2    = (uint*)alloc((size_t)E * 4);
    int*    off     = (int*)alloc((size_t)N * 4);
    int*    cnt     = (int*)alloc((size_t)N * 4);
    ushort* xb      = (ushort*)alloc((size_t)N * D * 2);
    ushort* a0b     = (ushort*)alloc((size_t)N * D * 2);
    ushort* a1b     = (ushort*)alloc((size_t)N * D * 2);
    ushort* Wt      = (ushort*)alloc((size_t)128 * 384 * 2);
    (void)ws_size; (void)in_sizes; (void)n_in; (void)out_size;

    hipMemsetAsync(cnt_b, 0, (size_t)NB * 4, stream);
    cvt_k         <<<(N * D / 4 + 255) / 256, 256, 0, stream>>>(x, xb);
    cvt_w_k       <<<(128 * 384 + 255) / 256, 256, 0, stream>>>(W, Wr, Wt);
    bucket_count_k<<<BINBLK, 256, 0, stream>>>(ei, cnt_b);
    bucket_scan_k <<<1, 1024, 0, stream>>>(cnt_b, bkt_off, cursor);
    bin_k         <<<BINBLK, 256, 0, stream>>>(ei, ea, cursor, pay);
    bucket_sort_k <<<NB, 256, 0, stream>>>(bkt_off, cursor, pay, pay2, off, cnt);
    edge_agg_k    <<<N / 4, 256, 0, stream>>>(xb, off, cnt, pay2, a0b, a1b);
    gemm_k        <<<(N + 127) / 128, 256, 0, stream>>>(a0b, a1b, xb, Wt, bias, out);
}

// Round 5
// 209.534 us; speedup vs baseline: 2.3288x; 1.1310x over previous
//
#include <hip/hip_runtime.h>

static constexpr int N = 50000;      // nodes
static constexpr int E = 1600000;    // edges
static constexpr int D = 128;        // feature dim (in == out)
static constexpr int NB = (N + 63) / 64;         // 782 buckets of 64 nodes
static constexpr int BINBLK = 512;               // bin blocks (E divides evenly)
static constexpr int CHUNK = E / BINBLK;         // 3125 edges per bin block
static constexpr int BKT_CAP = 3072;             // mean 2048, sigma ~45

typedef __attribute__((ext_vector_type(8))) short short8;   // 8 bf16
typedef __attribute__((ext_vector_type(4))) float f32x4;    // 4 fp32
typedef __attribute__((ext_vector_type(2))) float f32x2;    // 2 fp32 (pk ops)

__device__ __forceinline__ uint bf16rne2(float a, float b) {
    uint ua = __float_as_uint(a), ub = __float_as_uint(b);
    ua += 0x7fffu + ((ua >> 16) & 1u);
    ub += 0x7fffu + ((ub >> 16) & 1u);
    return (ua >> 16) | (ub & 0xffff0000u);
}

// fp32 -> bf16 (RNE) conversion of x, vectorized: 4 elems/thread.
__global__ void cvt_k(const float* __restrict__ x, ushort* __restrict__ xb) {
    int i = blockIdx.x * blockDim.x + threadIdx.x;
    if (i < N * D / 4) {
        float4 v = ((const float4*)x)[i];
        uint2 o = { bf16rne2(v.x, v.y), bf16rne2(v.z, v.w) };
        ((uint2*)xb)[i] = o;
    }
}

// Weight transpose + bf16: Wt[n][r], r in [0,384): r<256 -> W, r>=256 -> Wr.
__global__ void cvt_w_k(const float* __restrict__ W, const float* __restrict__ Wr,
                        ushort* __restrict__ Wt) {
    int i = blockIdx.x * blockDim.x + threadIdx.x;
    if (i < 128 * 384) {
        int n = i / 384, r = i % 384;
        float v = (r < 256) ? W[(size_t)r * 128 + n] : Wr[(size_t)(r - 256) * 128 + n];
        uint u = __float_as_uint(v);
        u += 0x7fffu + ((u >> 16) & 1u);
        Wt[(size_t)n * 384 + r] = (ushort)(u >> 16);
    }
}

// --------------------------------------- deterministic two-pass binning
// XCD swizzle: logically-adjacent chunks on the same XCD so adjacent payload
// runs share an L2 (kills cross-XCD partial-line write thrash).
__device__ __forceinline__ int logical_blk() {
    return (blockIdx.x & 7) * (BINBLK / 8) + (blockIdx.x >> 3);
}

// Pass A: per-block bucket histogram -> bh[j*BINBLK + b].
__global__ __launch_bounds__(256) void passA_k(const int* __restrict__ ei,
                                               int* __restrict__ bh) {
    __shared__ int hist[NB];
    int t = threadIdx.x;
    int b = logical_blk();
    for (int j = t; j < NB; j += 256) hist[j] = 0;
    __syncthreads();
    int b0 = b * CHUNK;
    for (int i = b0 + t; i < b0 + CHUNK; i += 256) {
        int dst = ei[E + i];
        if ((unsigned)dst < (unsigned)N) atomicAdd(&hist[dst >> 6], 1);
    }
    __syncthreads();
    for (int j = t; j < NB; j += 256) bh[j * BINBLK + b] = hist[j];
}

// Row scan: for bucket j, exclusive-scan bh[j][0..BINBLK) in place; total
// to cnt_b[j].
__global__ __launch_bounds__(512) void rowscan_k(int* __restrict__ bh,
                                                 int* __restrict__ cnt_b) {
    __shared__ int s[512];
    int j = blockIdx.x, t = threadIdx.x;
    int v = bh[j * BINBLK + t];
    s[t] = v;
    __syncthreads();
    for (int d = 1; d < 512; d <<= 1) {
        int add = (t >= d) ? s[t - d] : 0;
        int cur = s[t];
        __syncthreads();
        s[t] = cur + add;
        __syncthreads();
    }
    bh[j * BINBLK + t] = s[t] - v;          // exclusive within bucket row
    if (t == 511) cnt_b[j] = s[511];        // bucket total
}

// Total scan: exclusive scan of 782 bucket totals -> bkt_off.
__global__ __launch_bounds__(1024) void totscan_k(const int* __restrict__ cnt_b,
                                                  int* __restrict__ bkt_off) {
    __shared__ int s[1024];
    int t = threadIdx.x;
    int v = (t < NB) ? cnt_b[t] : 0;
    s[t] = v;
    __syncthreads();
    for (int d = 1; d < 1024; d <<= 1) {
        int add = (t >= d) ? s[t - d] : 0;
        int cur = s[t];
        __syncthreads();
        s[t] = cur + add;
        __syncthreads();
    }
    if (t < NB) bkt_off[t] = s[t] - v;
}

// Pass B: scatter with precomputed per-(block,bucket) bases; zero global
// atomics. Payload: [15:0]=src, [21:16]=dst&63, [31:22]=u quantized /1023.
__global__ __launch_bounds__(256) void passB_k(const int* __restrict__ ei,
                                               const float* __restrict__ ea,
                                               const int* __restrict__ bh,
                                               const int* __restrict__ bkt_off,
                                               uint* __restrict__ pay) {
    __shared__ int base[NB];
    __shared__ int hist[NB];
    int t = threadIdx.x;
    int b = logical_blk();
    for (int j = t; j < NB; j += 256) {
        base[j] = bkt_off[j] + bh[j * BINBLK + b];   // bh row is L2-resident
        hist[j] = 0;
    }
    __syncthreads();
    int b0 = b * CHUNK;
    for (int i = b0 + t; i < b0 + CHUNK; i += 256) {
        int dst = ei[E + i];
        if ((unsigned)dst >= (unsigned)N) continue;
        int src = ei[i];
        float u = fminf(fmaxf(ea[i], 0.0f), 1.0f);
        uint u10 = (uint)(u * 1023.0f + 0.5f);
        int bkt = dst >> 6;
        int r = atomicAdd(&hist[bkt], 1);
        pay[base[bkt] + r] = (u10 << 22) | ((uint)(dst & 63) << 16) | (uint)src;
    }
}

// Per-bucket LDS sort by dst_low -> coalesced sorted CSR + off/cnt.
// off[n] = END of node n's range, cnt[n] = degree.
__global__ __launch_bounds__(256) void bucket_sort_k(
        const int* __restrict__ bkt_off, const int* __restrict__ cnt_b,
        const uint* __restrict__ pay_in, uint* __restrict__ pay_out,
        int* __restrict__ off, int* __restrict__ cnt) {
    __shared__ uint srt[BKT_CAP];
    __shared__ int hist[64];
    __shared__ int off64[65];
    int b = blockIdx.x, t = threadIdx.x;
    int beg = bkt_off[b];
    int c = cnt_b[b];
    if (c > BKT_CAP) c = BKT_CAP;     // statistically impossible; safety
    if (t < 64) hist[t] = 0;
    __syncthreads();
    uint mypay[12]; int myrank[12];
#pragma unroll
    for (int k = 0; k < 12; ++k) {
        int i = t + k * 256;
        if (i < c) {
            uint p = pay_in[beg + i];
            mypay[k] = p;
            myrank[k] = atomicAdd(&hist[(p >> 16) & 63], 1);
        }
    }
    __syncthreads();
    if (t < 64) {
        int v = hist[t];
        int s = v;
        for (int d = 1; d < 64; d <<= 1) {
            int o = __shfl_up(s, d);
            if (t >= d) s += o;
        }
        off64[t] = s - v;             // exclusive
        if (t == 63) off64[64] = s;
    }
    __syncthreads();
#pragma unroll
    for (int k = 0; k < 12; ++k) {
        int i = t + k * 256;
        if (i < c) {
            uint p = mypay[k];
            srt[off64[(p >> 16) & 63] + myrank[k]] = p;
        }
    }
    __syncthreads();
    for (int i = t; i < c; i += 256) pay_out[beg + i] = srt[i];   // coalesced
    if (t < 64) {
        int node = b * 64 + t;
        if (node < N) {
            off[node] = beg + off64[t + 1];          // range end
            cnt[node] = off64[t + 1] - off64[t];
        }
    }
}

// ------------------------------------------------- per-node edge aggregation
// One wave per destination node; 16 lanes per edge (lane&15 -> 8-ch block),
// 4 edge-groups x 2-deep pipeline = 8 row-gathers in flight per wave.
// S/T identity: S = sum x, T = sum u*x; a0=(S-T)/deg, a1=T/deg. float2
// accumulators -> v_pk_add_f32 / v_pk_fma_f32.
__global__ __launch_bounds__(256) void edge_agg_k(
        const ushort* __restrict__ xb, const int* __restrict__ off,
        const int* __restrict__ cnt, const uint* __restrict__ pay,
        ushort* __restrict__ a0b, ushort* __restrict__ a1b) {
    int wave = (blockIdx.x * blockDim.x + threadIdx.x) >> 6;
    int lane = threadIdx.x & 63;
    if (wave >= N) return;
    int n   = wave;
    int end = off[n];
    int deg = cnt[n];
    int beg = end - deg;

    int grp = lane >> 4;
    int cl  = lane & 15;

    f32x2 S[4], T[4];
#pragma unroll
    for (int q = 0; q < 4; ++q) { S[q] = 0.f; T[q] = 0.f; }

    for (int base = beg; base < end; base += 64) {
        int m = end - base; if (m > 64) m = 64;
        uint pv = (lane < m) ? pay[base + lane] : 0u;
        for (int j = 0; 4 * j < m; j += 2) {
            int s0 = 4 * j + grp;
            int s1 = s0 + 4;
            uint p0 = (uint)__shfl((int)pv, s0);
            uint p1 = (uint)__shfl((int)pv, s1);
            bool g0 = s0 < m, g1 = s1 < m;
            uint4 v0 = make_uint4(0, 0, 0, 0), v1 = make_uint4(0, 0, 0, 0);
            if (g0) v0 = *(const uint4*)(xb + (size_t)(p0 & 0xffffu) * D + cl * 8);
            if (g1) v1 = *(const uint4*)(xb + (size_t)(p1 & 0xffffu) * D + cl * 8);
            if (g0) {
                float u = (float)(p0 >> 22) * (1.0f / 1023.0f);
                f32x2 u2 = {u, u};
                uint w[4] = {v0.x, v0.y, v0.z, v0.w};
#pragma unroll
                for (int q = 0; q < 4; ++q) {
                    f32x2 xv = { __uint_as_float(w[q] << 16),
                                 __uint_as_float(w[q] & 0xffff0000u) };
                    S[q] += xv;
                    T[q] = u2 * xv + T[q];
                }
            }
            if (g1) {
                float u = (float)(p1 >> 22) * (1.0f / 1023.0f);
                f32x2 u2 = {u, u};
                uint w[4] = {v1.x, v1.y, v1.z, v1.w};
#pragma unroll
                for (int q = 0; q < 4; ++q) {
                    f32x2 xv = { __uint_as_float(w[q] << 16),
                                 __uint_as_float(w[q] & 0xffff0000u) };
                    S[q] += xv;
                    T[q] = u2 * xv + T[q];
                }
            }
        }
    }
#pragma unroll
    for (int q = 0; q < 4; ++q) {
        S[q].x += __shfl_xor(S[q].x, 16);  S[q].x += __shfl_xor(S[q].x, 32);
        S[q].y += __shfl_xor(S[q].y, 16);  S[q].y += __shfl_xor(S[q].y, 32);
        T[q].x += __shfl_xor(T[q].x, 16);  T[q].x += __shfl_xor(T[q].x, 32);
        T[q].y += __shfl_xor(T[q].y, 16);  T[q].y += __shfl_xor(T[q].y, 32);
    }
    float inv = 1.0f / fmaxf((float)deg, 1.0f);
    if (lane < 16) {
        uint4 oa = { bf16rne2((S[0].x - T[0].x) * inv, (S[0].y - T[0].y) * inv),
                     bf16rne2((S[1].x - T[1].x) * inv, (S[1].y - T[1].y) * inv),
                     bf16rne2((S[2].x - T[2].x) * inv, (S[2].y - T[2].y) * inv),
                     bf16rne2((S[3].x - T[3].x) * inv, (S[3].y - T[3].y) * inv) };
        uint4 ob = { bf16rne2(T[0].x * inv, T[0].y * inv),
                     bf16rne2(T[1].x * inv, T[1].y * inv),
                     bf16rne2(T[2].x * inv, T[2].y * inv),
                     bf16rne2(T[3].x * inv, T[3].y * inv) };
        *(uint4*)(a0b + (size_t)n * D + cl * 8) = oa;
        *(uint4*)(a1b + (size_t)n * D + cl * 8) = ob;
    }
}

// ------------------------------------------------------------- output GEMM
// out = [a0|a1|x] (M=50000, K=384, bf16) @ Wt^T + bias. 128x128 tile,
// 4 waves 2x2, 16x16x32 bf16 MFMA, BK=32.
__global__ __launch_bounds__(256) void gemm_k(
        const ushort* __restrict__ a0b, const ushort* __restrict__ a1b,
        const ushort* __restrict__ xb, const ushort* __restrict__ Wt,
        const float* __restrict__ bias, float* __restrict__ out) {
    constexpr int LST = 40;
    __shared__ ushort As[128 * LST];
    __shared__ ushort Bs[128 * LST];

    int t    = threadIdx.x;
    int lane = t & 63;
    int w    = t >> 6;
    int r2   = w >> 1, c2 = w & 1;
    int q    = lane >> 4;
    int l16  = lane & 15;
    int row0 = blockIdx.x * 128;

    f32x4 acc[4][4];
#pragma unroll
    for (int i = 0; i < 4; ++i)
#pragma unroll
        for (int j = 0; j < 4; ++j) acc[i][j] = 0.f;

    const ushort* Asrc[3] = {a0b, a1b, xb};

    for (int kt = 0; kt < 384; kt += 32) {
        const ushort* Ab = Asrc[kt >> 7];
        int ko = kt & 127;
#pragma unroll
        for (int h = 0; h < 2; ++h) {
            int s  = t + h * 256;
            int r  = s >> 2;
            int q4 = s & 3;
            int rg = row0 + r;
            uint4 av = make_uint4(0, 0, 0, 0);
            if (rg < N) av = *(const uint4*)(Ab + (size_t)rg * 128 + ko + q4 * 8);
            *(uint4*)&As[r * LST + q4 * 8] = av;
            uint4 bv = *(const uint4*)(Wt + (size_t)r * 384 + kt + q4 * 8);
            *(uint4*)&Bs[r * LST + q4 * 8] = bv;
        }
        __syncthreads();
        short8 af[4], bf[4];
#pragma unroll
        for (int mt = 0; mt < 4; ++mt)
            af[mt] = *(const short8*)&As[(r2 * 64 + mt * 16 + l16) * LST + q * 8];
#pragma unroll
        for (int nt = 0; nt < 4; ++nt)
            bf[nt] = *(const short8*)&Bs[(c2 * 64 + nt * 16 + l16) * LST + q * 8];
#pragma unroll
        for (int mt = 0; mt < 4; ++mt)
#pragma unroll
            for (int nt = 0; nt < 4; ++nt)
                acc[mt][nt] = __builtin_amdgcn_mfma_f32_16x16x32_bf16(
                    af[mt], bf[nt], acc[mt][nt], 0, 0, 0);
        __syncthreads();
    }

#pragma unroll
    for (int nt = 0; nt < 4; ++nt) {
        int col = c2 * 64 + nt * 16 + l16;
        float bb = bias[col];
#pragma unroll
        for (int mt = 0; mt < 4; ++mt) {
#pragma unroll
            for (int r = 0; r < 4; ++r) {
                int row = row0 + r2 * 64 + mt * 16 + q * 4 + r;
                if (row < N) out[(size_t)row * 128 + col] = acc[mt][nt][r] + bb;
            }
        }
    }
}

// ------------------------------------------------------------------ launch
extern "C" void kernel_launch(void* const* d_in, const int* in_sizes, int n_in,
                              void* d_out, int out_size, void* d_ws, size_t ws_size,
                              hipStream_t stream) {
    const float* x    = (const float*)d_in[0];
    const int*   ei   = (const int*)d_in[1];   // [2, E] int32
    const float* ea   = (const float*)d_in[2]; // [E, 1]
    const float* W    = (const float*)d_in[3]; // [2, 128, 128]
    const float* Wr   = (const float*)d_in[4]; // [128, 128]
    const float* bias = (const float*)d_in[5]; // [128]
    float* out = (float*)d_out;

    char* ws = (char*)d_ws;
    size_t o = 0;
    auto alloc = [&](size_t bytes) -> void* {
        void* p = ws + o;
        o = (o + bytes + 255) & ~(size_t)255;
        return p;
    };
    int*    bh      = (int*)alloc((size_t)NB * BINBLK * 4);
    int*    cnt_b   = (int*)alloc((size_t)NB * 4);
    int*    bkt_off = (int*)alloc((size_t)NB * 4);
    uint*   pay     = (uint*)alloc((size_t)E * 4);
    uint*   pay2    = (uint*)alloc((size_t)E * 4);
    int*    off     = (int*)alloc((size_t)N * 4);
    int*    cnt     = (int*)alloc((size_t)N * 4);
    ushort* xb      = (ushort*)alloc((size_t)N * D * 2);
    ushort* a0b     = (ushort*)alloc((size_t)N * D * 2);
    ushort* a1b     = (ushort*)alloc((size_t)N * D * 2);
    ushort* Wt      = (ushort*)alloc((size_t)128 * 384 * 2);
    (void)ws_size; (void)in_sizes; (void)n_in; (void)out_size;

    cvt_k        <<<(N * D / 4 + 255) / 256, 256, 0, stream>>>(x, xb);
    cvt_w_k      <<<(128 * 384 + 255) / 256, 256, 0, stream>>>(W, Wr, Wt);
    passA_k      <<<BINBLK, 256, 0, stream>>>(ei, bh);
    rowscan_k    <<<NB, 512, 0, stream>>>(bh, cnt_b);
    totscan_k    <<<1, 1024, 0, stream>>>(cnt_b, bkt_off);
    passB_k      <<<BINBLK, 256, 0, stream>>>(ei, ea, bh, bkt_off, pay);
    bucket_sort_k<<<NB, 256, 0, stream>>>(bkt_off, cnt_b, pay, pay2, off, cnt);
    edge_agg_k   <<<N / 4, 256, 0, stream>>>(xb, off, cnt, pay2, a0b, a1b);
    gemm_k       <<<(N + 127) / 128, 256, 0, stream>>>(a0b, a1b, xb, Wt, bias, out);
}

// Round 6
// 195.248 us; speedup vs baseline: 2.4992x; 1.0732x over previous
//
#include <hip/hip_runtime.h>

static constexpr int N = 50000;      // nodes
static constexpr int E = 1600000;    // edges
static constexpr int D = 128;        // feature dim (in == out)
static constexpr int NB = (N + 63) / 64;         // 782 buckets of 64 nodes
static constexpr int BINBLK = 512;               // bin blocks (E divides evenly)
static constexpr int CHUNK = E / BINBLK;         // 3125 edges per bin block
static constexpr int BKT_CAP = 3072;             // mean 2048, sigma ~45

typedef __attribute__((ext_vector_type(8))) short short8;   // 8 bf16
typedef __attribute__((ext_vector_type(4))) float f32x4;    // 4 fp32
typedef __attribute__((ext_vector_type(2))) float f32x2;    // 2 fp32 (pk ops)

__device__ __forceinline__ uint bf16rne2(float a, float b) {
    uint ua = __float_as_uint(a), ub = __float_as_uint(b);
    ua += 0x7fffu + ((ua >> 16) & 1u);
    ub += 0x7fffu + ((ub >> 16) & 1u);
    return (ua >> 16) | (ub & 0xffff0000u);
}

// fp32 -> bf16 (RNE) conversion of x, vectorized: 4 elems/thread.
__global__ void cvt_k(const float* __restrict__ x, ushort* __restrict__ xb) {
    int i = blockIdx.x * blockDim.x + threadIdx.x;
    if (i < N * D / 4) {
        float4 v = ((const float4*)x)[i];
        uint2 o = { bf16rne2(v.x, v.y), bf16rne2(v.z, v.w) };
        ((uint2*)xb)[i] = o;
    }
}

// Weight transpose + bf16: Wt[n][r], r in [0,384): r<256 -> W, r>=256 -> Wr.
__global__ void cvt_w_k(const float* __restrict__ W, const float* __restrict__ Wr,
                        ushort* __restrict__ Wt) {
    int i = blockIdx.x * blockDim.x + threadIdx.x;
    if (i < 128 * 384) {
        int n = i / 384, r = i % 384;
        float v = (r < 256) ? W[(size_t)r * 128 + n] : Wr[(size_t)(r - 256) * 128 + n];
        uint u = __float_as_uint(v);
        u += 0x7fffu + ((u >> 16) & 1u);
        Wt[(size_t)n * 384 + r] = (ushort)(u >> 16);
    }
}

// --------------------------------------- deterministic two-pass binning
// XCD swizzle: logically-adjacent chunks on the same XCD so adjacent payload
// runs share an L2 (kills cross-XCD partial-line write thrash).
__device__ __forceinline__ int logical_blk() {
    return (blockIdx.x & 7) * (BINBLK / 8) + (blockIdx.x >> 3);
}

// Pass A: per-block bucket histogram -> bh[j*BINBLK + b]. 16 waves/block for
// latency hiding (R5 lesson: 4-wave blocks at 2/CU were latency-bound).
__global__ __launch_bounds__(1024) void passA_k(const int* __restrict__ ei,
                                                int* __restrict__ bh) {
    __shared__ int hist[NB];
    int t = threadIdx.x;
    int b = logical_blk();
    for (int j = t; j < NB; j += 1024) hist[j] = 0;
    __syncthreads();
    int b0 = b * CHUNK;
    for (int i = b0 + t; i < b0 + CHUNK; i += 1024) {
        int dst = ei[E + i];
        if ((unsigned)dst < (unsigned)N) atomicAdd(&hist[dst >> 6], 1);
    }
    __syncthreads();
    for (int j = t; j < NB; j += 1024) bh[j * BINBLK + b] = hist[j];
}

// Row scan: for bucket j, exclusive-scan bh[j][0..BINBLK) in place; total
// to cnt_b[j].
__global__ __launch_bounds__(512) void rowscan_k(int* __restrict__ bh,
                                                 int* __restrict__ cnt_b) {
    __shared__ int s[512];
    int j = blockIdx.x, t = threadIdx.x;
    int v = bh[j * BINBLK + t];
    s[t] = v;
    __syncthreads();
    for (int d = 1; d < 512; d <<= 1) {
        int add = (t >= d) ? s[t - d] : 0;
        int cur = s[t];
        __syncthreads();
        s[t] = cur + add;
        __syncthreads();
    }
    bh[j * BINBLK + t] = s[t] - v;          // exclusive within bucket row
    if (t == 511) cnt_b[j] = s[511];        // bucket total
}

// Total scan: exclusive scan of 782 bucket totals -> bkt_off.
__global__ __launch_bounds__(1024) void totscan_k(const int* __restrict__ cnt_b,
                                                  int* __restrict__ bkt_off) {
    __shared__ int s[1024];
    int t = threadIdx.x;
    int v = (t < NB) ? cnt_b[t] : 0;
    s[t] = v;
    __syncthreads();
    for (int d = 1; d < 1024; d <<= 1) {
        int add = (t >= d) ? s[t - d] : 0;
        int cur = s[t];
        __syncthreads();
        s[t] = cur + add;
        __syncthreads();
    }
    if (t < NB) bkt_off[t] = s[t] - v;
}

// Pass B: scatter with precomputed per-(block,bucket) bases; zero global
// atomics. Payload: [15:0]=src, [21:16]=dst&63, [31:22]=u quantized /1023.
__global__ __launch_bounds__(1024) void passB_k(const int* __restrict__ ei,
                                                const float* __restrict__ ea,
                                                const int* __restrict__ bh,
                                                const int* __restrict__ bkt_off,
                                                uint* __restrict__ pay) {
    __shared__ int base[NB];
    __shared__ int hist[NB];
    int t = threadIdx.x;
    int b = logical_blk();
    for (int j = t; j < NB; j += 1024) {
        base[j] = bkt_off[j] + bh[j * BINBLK + b];
        hist[j] = 0;
    }
    __syncthreads();
    int b0 = b * CHUNK;
    for (int i = b0 + t; i < b0 + CHUNK; i += 1024) {
        int dst = ei[E + i];
        if ((unsigned)dst >= (unsigned)N) continue;
        int src = ei[i];
        float u = fminf(fmaxf(ea[i], 0.0f), 1.0f);
        uint u10 = (uint)(u * 1023.0f + 0.5f);
        int bkt = dst >> 6;
        int r = atomicAdd(&hist[bkt], 1);
        pay[base[bkt] + r] = (u10 << 22) | ((uint)(dst & 63) << 16) | (uint)src;
    }
}

// --------------------------- fused per-bucket sort + per-node aggregation
// One 1024-thread WG per bucket (64 nodes). Phase 1: LDS-rank the bucket's
// payload by dst_low6 (off64 gives per-node ranges; no global CSR needed).
// Phase 2: 16 waves x 4 groups of 16 lanes; group = one node; lane = 8 chs.
// Payload reads are LDS broadcasts (no shuffles, no guards); each lane's
// channels are complete locally (no cross-lane reduce).
__global__ __launch_bounds__(1024) void sortagg_k(
        const ushort* __restrict__ xb, const int* __restrict__ bkt_off,
        const int* __restrict__ cnt_b, const uint* __restrict__ pay,
        ushort* __restrict__ a0b, ushort* __restrict__ a1b) {
    __shared__ uint srt[BKT_CAP];
    __shared__ int hist[64];
    __shared__ int off64[65];
    int b = blockIdx.x, t = threadIdx.x;
    int beg = bkt_off[b];
    int c = cnt_b[b];
    if (c > BKT_CAP) c = BKT_CAP;     // statistically impossible; safety
    if (t < 64) hist[t] = 0;
    __syncthreads();
    uint mypay[3]; int myrank[3];
#pragma unroll
    for (int k = 0; k < 3; ++k) {
        int i = t + k * 1024;
        if (i < c) {
            uint p = pay[beg + i];
            mypay[k] = p;
            myrank[k] = atomicAdd(&hist[(p >> 16) & 63], 1);
        }
    }
    __syncthreads();
    if (t < 64) {
        int v = hist[t];
        int s = v;
        for (int d = 1; d < 64; d <<= 1) {
            int o = __shfl_up(s, d);
            if (t >= d) s += o;
        }
        off64[t] = s - v;             // exclusive
        if (t == 63) off64[64] = s;
    }
    __syncthreads();
#pragma unroll
    for (int k = 0; k < 3; ++k) {
        int i = t + k * 1024;
        if (i < c) {
            uint p = mypay[k];
            srt[off64[(p >> 16) & 63] + myrank[k]] = p;
        }
    }
    __syncthreads();

    // ---- aggregation: group (wave, grp) -> local node nloc
    int lane = t & 63;
    int wv   = t >> 6;            // 0..15
    int grp  = (lane >> 4);       // 0..3
    int cl   = lane & 15;         // channel block: chs [8*cl, 8*cl+8)
    int nloc = wv * 4 + grp;      // 0..63
    int s0 = off64[nloc], s1 = off64[nloc + 1];
    int deg = s1 - s0;

    f32x2 S[4], T[4];
#pragma unroll
    for (int q = 0; q < 4; ++q) { S[q] = 0.f; T[q] = 0.f; }

    int j = s0;
    for (; j + 1 < s1; j += 2) {           // 2-deep pipeline
        uint p0 = srt[j], p1 = srt[j + 1];
        uint4 v0 = *(const uint4*)(xb + (size_t)(p0 & 0xffffu) * D + cl * 8);
        uint4 v1 = *(const uint4*)(xb + (size_t)(p1 & 0xffffu) * D + cl * 8);
        {
            float u = (float)(p0 >> 22) * (1.0f / 1023.0f);
            f32x2 u2 = {u, u};
            uint w[4] = {v0.x, v0.y, v0.z, v0.w};
#pragma unroll
            for (int q = 0; q < 4; ++q) {
                f32x2 xv = { __uint_as_float(w[q] << 16),
                             __uint_as_float(w[q] & 0xffff0000u) };
                S[q] += xv;
                T[q] = u2 * xv + T[q];
            }
        }
        {
            float u = (float)(p1 >> 22) * (1.0f / 1023.0f);
            f32x2 u2 = {u, u};
            uint w[4] = {v1.x, v1.y, v1.z, v1.w};
#pragma unroll
            for (int q = 0; q < 4; ++q) {
                f32x2 xv = { __uint_as_float(w[q] << 16),
                             __uint_as_float(w[q] & 0xffff0000u) };
                S[q] += xv;
                T[q] = u2 * xv + T[q];
            }
        }
    }
    if (j < s1) {
        uint p0 = srt[j];
        uint4 v0 = *(const uint4*)(xb + (size_t)(p0 & 0xffffu) * D + cl * 8);
        float u = (float)(p0 >> 22) * (1.0f / 1023.0f);
        f32x2 u2 = {u, u};
        uint w[4] = {v0.x, v0.y, v0.z, v0.w};
#pragma unroll
        for (int q = 0; q < 4; ++q) {
            f32x2 xv = { __uint_as_float(w[q] << 16),
                         __uint_as_float(w[q] & 0xffff0000u) };
            S[q] += xv;
            T[q] = u2 * xv + T[q];
        }
    }

    int node = b * 64 + nloc;
    if (node < N) {
        float inv = 1.0f / fmaxf((float)deg, 1.0f);
        uint4 oa = { bf16rne2((S[0].x - T[0].x) * inv, (S[0].y - T[0].y) * inv),
                     bf16rne2((S[1].x - T[1].x) * inv, (S[1].y - T[1].y) * inv),
                     bf16rne2((S[2].x - T[2].x) * inv, (S[2].y - T[2].y) * inv),
                     bf16rne2((S[3].x - T[3].x) * inv, (S[3].y - T[3].y) * inv) };
        uint4 ob = { bf16rne2(T[0].x * inv, T[0].y * inv),
                     bf16rne2(T[1].x * inv, T[1].y * inv),
                     bf16rne2(T[2].x * inv, T[2].y * inv),
                     bf16rne2(T[3].x * inv, T[3].y * inv) };
        *(uint4*)(a0b + (size_t)node * D + cl * 8) = oa;
        *(uint4*)(a1b + (size_t)node * D + cl * 8) = ob;
    }
}

// ------------------------------------------------------------- output GEMM
// out = [a0|a1|x] (M=50000, K=384, bf16) @ Wt^T + bias. 128x128 tile,
// 4 waves 2x2, 16x16x32 bf16 MFMA, BK=32.
__global__ __launch_bounds__(256) void gemm_k(
        const ushort* __restrict__ a0b, const ushort* __restrict__ a1b,
        const ushort* __restrict__ xb, const ushort* __restrict__ Wt,
        const float* __restrict__ bias, float* __restrict__ out) {
    constexpr int LST = 40;
    __shared__ ushort As[128 * LST];
    __shared__ ushort Bs[128 * LST];

    int t    = threadIdx.x;
    int lane = t & 63;
    int w    = t >> 6;
    int r2   = w >> 1, c2 = w & 1;
    int q    = lane >> 4;
    int l16  = lane & 15;
    int row0 = blockIdx.x * 128;

    f32x4 acc[4][4];
#pragma unroll
    for (int i = 0; i < 4; ++i)
#pragma unroll
        for (int j = 0; j < 4; ++j) acc[i][j] = 0.f;

    const ushort* Asrc[3] = {a0b, a1b, xb};

    for (int kt = 0; kt < 384; kt += 32) {
        const ushort* Ab = Asrc[kt >> 7];
        int ko = kt & 127;
#pragma unroll
        for (int h = 0; h < 2; ++h) {
            int s  = t + h * 256;
            int r  = s >> 2;
            int q4 = s & 3;
            int rg = row0 + r;
            uint4 av = make_uint4(0, 0, 0, 0);
            if (rg < N) av = *(const uint4*)(Ab + (size_t)rg * 128 + ko + q4 * 8);
            *(uint4*)&As[r * LST + q4 * 8] = av;
            uint4 bv = *(const uint4*)(Wt + (size_t)r * 384 + kt + q4 * 8);
            *(uint4*)&Bs[r * LST + q4 * 8] = bv;
        }
        __syncthreads();
        short8 af[4], bf[4];
#pragma unroll
        for (int mt = 0; mt < 4; ++mt)
            af[mt] = *(const short8*)&As[(r2 * 64 + mt * 16 + l16) * LST + q * 8];
#pragma unroll
        for (int nt = 0; nt < 4; ++nt)
            bf[nt] = *(const short8*)&Bs[(c2 * 64 + nt * 16 + l16) * LST + q * 8];
#pragma unroll
        for (int mt = 0; mt < 4; ++mt)
#pragma unroll
            for (int nt = 0; nt < 4; ++nt)
                acc[mt][nt] = __builtin_amdgcn_mfma_f32_16x16x32_bf16(
                    af[mt], bf[nt], acc[mt][nt], 0, 0, 0);
        __syncthreads();
    }

#pragma unroll
    for (int nt = 0; nt < 4; ++nt) {
        int col = c2 * 64 + nt * 16 + l16;
        float bb = bias[col];
#pragma unroll
        for (int mt = 0; mt < 4; ++mt) {
#pragma unroll
            for (int r = 0; r < 4; ++r) {
                int row = row0 + r2 * 64 + mt * 16 + q * 4 + r;
                if (row < N) out[(size_t)row * 128 + col] = acc[mt][nt][r] + bb;
            }
        }
    }
}

// ------------------------------------------------------------------ launch
extern "C" void kernel_launch(void* const* d_in, const int* in_sizes, int n_in,
                              void* d_out, int out_size, void* d_ws, size_t ws_size,
                              hipStream_t stream) {
    const float* x    = (const float*)d_in[0];
    const int*   ei   = (const int*)d_in[1];   // [2, E] int32
    const float* ea   = (const float*)d_in[2]; // [E, 1]
    const float* W    = (const float*)d_in[3]; // [2, 128, 128]
    const float* Wr   = (const float*)d_in[4]; // [128, 128]
    const float* bias = (const float*)d_in[5]; // [128]
    float* out = (float*)d_out;

    char* ws = (char*)d_ws;
    size_t o = 0;
    auto alloc = [&](size_t bytes) -> void* {
        void* p = ws + o;
        o = (o + bytes + 255) & ~(size_t)255;
        return p;
    };
    int*    bh      = (int*)alloc((size_t)NB * BINBLK * 4);
    int*    cnt_b   = (int*)alloc((size_t)NB * 4);
    int*    bkt_off = (int*)alloc((size_t)NB * 4);
    uint*   pay     = (uint*)alloc((size_t)E * 4);
    ushort* xb      = (ushort*)alloc((size_t)N * D * 2);
    ushort* a0b     = (ushort*)alloc((size_t)N * D * 2);
    ushort* a1b     = (ushort*)alloc((size_t)N * D * 2);
    ushort* Wt      = (ushort*)alloc((size_t)128 * 384 * 2);
    (void)ws_size; (void)in_sizes; (void)n_in; (void)out_size;

    cvt_k    <<<(N * D / 4 + 255) / 256, 256, 0, stream>>>(x, xb);
    cvt_w_k  <<<(128 * 384 + 255) / 256, 256, 0, stream>>>(W, Wr, Wt);
    passA_k  <<<BINBLK, 1024, 0, stream>>>(ei, bh);
    rowscan_k<<<NB, 512, 0, stream>>>(bh, cnt_b);
    totscan_k<<<1, 1024, 0, stream>>>(cnt_b, bkt_off);
    passB_k  <<<BINBLK, 1024, 0, stream>>>(ei, ea, bh, bkt_off, pay);
    sortagg_k<<<NB, 1024, 0, stream>>>(xb, bkt_off, cnt_b, pay, a0b, a1b);
    gemm_k   <<<(N + 127) / 128, 256, 0, stream>>>(a0b, a1b, xb, Wt, bias, out);
}